// Round 6
// baseline (1420.014 us; speedup 1.0000x reference)
//
#include <hip/hip_runtime.h>
#include <hip/hip_bf16.h>

#define N_NODES 50000
#define N_EDGES 800000
#define DIM     256
#define NLAYERS 4
#define EPS     1e-5f
#define SCAN_B  196   // ceil(50000/256)
#define MASK40  ((1ULL << 40) - 1)
#define EPACK_CAP (N_EDGES + 15 * N_NODES + 32)   // CSR padded to 16
#define ASTRIDE 258   // LDS A-tile row stride (elems)
#define SSTRIDE 258   // consumer stripe row stride (elems)
#define NTILES  1563  // ceil(50000/32)
#define GRIDB   512   // persistent blocks (2/CU)

typedef __bf16 bf16x8 __attribute__((ext_vector_type(8)));
typedef float  f32x4  __attribute__((ext_vector_type(4)));
typedef float  f32x2  __attribute__((ext_vector_type(2)));
typedef unsigned short u16x8 __attribute__((ext_vector_type(8)));
typedef unsigned short u16x4 __attribute__((ext_vector_type(4)));
typedef int            i32x4 __attribute__((ext_vector_type(4)));
typedef unsigned int   u32x2 __attribute__((ext_vector_type(2)));

__device__ __forceinline__ unsigned short f2b(float f) {
    __hip_bfloat16 h = __float2bfloat16(f);
    return __builtin_bit_cast(unsigned short, h);
}
__device__ __forceinline__ float b2f(unsigned short u) {
    unsigned int v = ((unsigned int)u) << 16;
    return __builtin_bit_cast(float, v);
}
// exact-GELU via Abramowitz-Stegun 7.1.26 erf (|erf err| <= 1.5e-7)
__device__ __forceinline__ float gelu_exact(float x) {
    float ax = fabsf(x) * 0.70710678118654752f;
    float t  = 1.0f / (1.0f + 0.3275911f * ax);
    float p  = t * (0.254829592f + t * (-0.284496736f +
               t * (1.421413741f + t * (-1.453152027f + t * 1.061405429f))));
    float er = 1.0f - p * __expf(-ax * ax);
    er = (x < 0.0f) ? -er : er;
    return 0.5f * x * (1.0f + er);
}
// pack 4 f32 -> 4 fp8 e4m3 (OCP on gfx950), RNE
__device__ __forceinline__ unsigned int pack_fp8x4(float a, float b, float c, float d) {
    int v = 0;
    v = __builtin_amdgcn_cvt_pk_fp8_f32(a, b, v, false);
    v = __builtin_amdgcn_cvt_pk_fp8_f32(c, d, v, true);
    return (unsigned int)v;
}

// ---- setup kernels ------------------------------------------------------
__global__ __launch_bounds__(256) void hist_kernel(const int* __restrict__ dst,
                                                   const float* __restrict__ w,
                                                   unsigned long long* __restrict__ cnt64,
                                                   int* __restrict__ rank) {
    int e = blockIdx.x * 256 + threadIdx.x;
    if (e >= N_EDGES) return;
    int d = dst[e];
    unsigned long long wfix = (unsigned long long)(w[e] * 4294967296.0f);
    unsigned long long old = atomicAdd(&cnt64[d], (1ULL << 40) | wfix);
    rank[e] = (int)(old >> 40);
}

__global__ __launch_bounds__(256) void scan_a_kernel(const unsigned long long* __restrict__ cnt64,
                                                     float* __restrict__ dinv,
                                                     int* __restrict__ bsum) {
    __shared__ int l[256];
    int i = blockIdx.x * 256 + threadIdx.x;
    int pc = 0;
    if (i < N_NODES) {
        unsigned long long v = cnt64[i];
        int cnt = (int)(v >> 40);
        float sw = (float)(v & MASK40) * 2.3283064365386963e-10f;  // *2^-32
        dinv[i] = rsqrtf(1.0f + sw);
        pc = (cnt + 15) & ~15;
    }
    l[threadIdx.x] = pc;
    __syncthreads();
    for (int o = 128; o > 0; o >>= 1) {
        if (threadIdx.x < o) l[threadIdx.x] += l[threadIdx.x + o];
        __syncthreads();
    }
    if (threadIdx.x == 0) bsum[blockIdx.x] = l[0];
}

__global__ __launch_bounds__(256) void scan_b_kernel(const int* __restrict__ bsum,
                                                     int* __restrict__ boff,
                                                     int* __restrict__ rowptr) {
    __shared__ int l[256];
    int t = threadIdx.x;
    l[t] = (t < SCAN_B) ? bsum[t] : 0;
    __syncthreads();
    if (t == 0) {
        int run = 0;
        for (int j = 0; j < SCAN_B; ++j) { int v = l[j]; l[j] = run; run += v; }
        rowptr[N_NODES] = run;
    }
    __syncthreads();
    boff[t] = l[t];
}

__global__ __launch_bounds__(256) void scan_c_kernel(const unsigned long long* __restrict__ cnt64,
                                                     const int* __restrict__ boff,
                                                     int* __restrict__ rowptr) {
    __shared__ int l[256];
    int i = blockIdx.x * 256 + threadIdx.x;
    int pc = 0;
    if (i < N_NODES) {
        int cnt = (int)(cnt64[i] >> 40);
        pc = (cnt + 15) & ~15;
    }
    l[threadIdx.x] = pc;
    __syncthreads();
    if (threadIdx.x == 0) {
        int run = 0;
        for (int j = 0; j < 256; ++j) { int v = l[j]; l[j] = run; run += v; }
    }
    __syncthreads();
    if (i < N_NODES) rowptr[i] = boff[blockIdx.x] + l[threadIdx.x];
}

// No atomics: position = rowptr[dst] + rank.  epack.x = src byte-offset (src*256, fp8 rows).
__global__ __launch_bounds__(256) void fill_kernel(const int* __restrict__ src,
                                                   const int* __restrict__ dst,
                                                   const float* __restrict__ w,
                                                   const float* __restrict__ dinv,
                                                   const int* __restrict__ rowptr,
                                                   const int* __restrict__ rank,
                                                   int2* __restrict__ epack) {
    int e = blockIdx.x * 256 + threadIdx.x;
    if (e >= N_EDGES) return;
    int s = src[e], d = dst[e];
    float c = dinv[s] * w[e] * dinv[d];
    int p = rowptr[d] + rank[e];
    epack[p] = make_int2(s << 8, __float_as_int(c));
}

// Fragment-major weights: Wt[m][ks][n][ke], ks=K-step(32), n=out chan, ke=k%32.
__global__ __launch_bounds__(256) void convw_kernel(const float* __restrict__ conv_w,
                                                    const float* __restrict__ post_w,
                                                    unsigned short* __restrict__ Wt) {
    int idx = blockIdx.x * 256 + threadIdx.x;
    if (idx >= 5 * 65536) return;
    int m  = idx >> 16;
    int r  = idx & 65535;
    int ks = r >> 13;          // 0..7
    int n  = (r >> 5) & 255;   // out chan
    int ke = r & 31;           // k within step
    int k  = ks * 32 + ke;
    float v = (m < 4) ? conv_w[m * 65536 + k * 256 + n] : post_w[k * 256 + n];
    Wt[idx] = f2b(v);
}

// wave-per-row: Z8 = fp8(LN0(emb)), Hbf = bf16(emb)  (used once)
__global__ __launch_bounds__(256) void ln_cast_kernel(const float* __restrict__ H,
                                                      const float* __restrict__ lnw,
                                                      const float* __restrict__ lnb,
                                                      unsigned char* __restrict__ Z8,
                                                      unsigned short* __restrict__ Hbf) {
    int row = blockIdx.x * 4 + (threadIdx.x >> 6);
    int lane = threadIdx.x & 63;
    const float4 x = *(const float4*)(H + (size_t)row * DIM + lane * 4);
    float s = x.x + x.y + x.z + x.w;
    for (int o = 32; o > 0; o >>= 1) s += __shfl_xor(s, o);
    float mu = s * (1.0f / DIM);
    float d0 = x.x - mu, d1 = x.y - mu, d2 = x.z - mu, d3 = x.w - mu;
    float v = d0 * d0 + d1 * d1 + d2 * d2 + d3 * d3;
    for (int o = 32; o > 0; o >>= 1) v += __shfl_xor(v, o);
    float rs = rsqrtf(v * (1.0f / DIM) + EPS);
    const float4 ww = *(const float4*)(lnw + lane * 4);
    const float4 bb = *(const float4*)(lnb + lane * 4);
    float z0 = d0 * rs * ww.x + bb.x;
    float z1 = d1 * rs * ww.y + bb.y;
    float z2 = d2 * rs * ww.z + bb.z;
    float z3 = d3 * rs * ww.w + bb.w;
    *(unsigned int*)(Z8 + (size_t)row * DIM + lane * 4) = pack_fp8x4(z0, z1, z2, z3);
    ushort4 h4;
    h4.x = f2b(x.x); h4.y = f2b(x.y); h4.z = f2b(x.z); h4.w = f2b(x.w);
    *(ushort4*)(Hbf + (size_t)row * DIM + lane * 4) = h4;
}

// ---- fused layer, wave-specialized producer/consumer --------------------
// 384 threads: waves 0-3 gather tile t+1 into LDS dbuf; waves 4-5 consume
// tile t (16 nodes x 256 chans each: K-loop, wave-private stripe transpose,
// bias+GELU+residual+LN+Z8 -- no cross-wave deps). One barrier per tile.
__global__ __launch_bounds__(384, 4) void layer_kernel(const unsigned char* __restrict__ Z8in,
                                                       const int* __restrict__ rowptr,
                                                       const int2* __restrict__ epack,
                                                       const float* __restrict__ dinv,
                                                       const unsigned short* __restrict__ Bt,
                                                       const float* __restrict__ bias,
                                                       unsigned short* __restrict__ Hbf,
                                                       const float* __restrict__ lnw,
                                                       const float* __restrict__ lnb,
                                                       unsigned char* __restrict__ Z8out,
                                                       int doLN) {
    __shared__ unsigned short abuf[2][32 * ASTRIDE];   // 33.0 KB gather dbuf
    __shared__ unsigned short stripe[2][16 * SSTRIDE]; // 16.5 KB per-consumer-wave
    int tid = threadIdx.x;
    int wave = tid >> 6;
    int lane = tid & 63;
    int q = lane >> 4;
    int c16 = lane & 15;
    int g = lane >> 5;           // gather half id
    int colB = (lane & 31) * 8;  // gather: elem offset of this lane's 8 fp8 elems

    int nt = (NTILES - blockIdx.x + GRIDB - 1) / GRIDB;   // tiles for this block

    // ---------------- producer: gather one 32-node tile into abuf[buf] ----
    auto gather_tile = [&](int tile, int buf) {
        int mbase = tile * 32;
        for (int i = 0; i < 8; ++i) {
            int nl = wave * 8 + i;
            int node = mbase + nl;
            f32x2 a0 = {0.f, 0.f}, a1 = a0, a2 = a0, a3 = a0;
            if (node < N_NODES) {
                float di = dinv[node];
                float scg = (g == 0) ? di * di : 0.0f;
                const u32x2 zs = *(const u32x2*)(Z8in + (size_t)node * DIM + colB);
                {
                    f32x2 p0 = __builtin_amdgcn_cvt_pk_f32_fp8(zs[0], false);
                    f32x2 p1 = __builtin_amdgcn_cvt_pk_f32_fp8(zs[0], true);
                    f32x2 p2 = __builtin_amdgcn_cvt_pk_f32_fp8(zs[1], false);
                    f32x2 p3 = __builtin_amdgcn_cvt_pk_f32_fp8(zs[1], true);
                    a0 = scg * p0; a1 = scg * p1; a2 = scg * p2; a3 = scg * p3;
                }
                int e0 = rowptr[node], e1 = rowptr[node + 1];
                for (int e = e0; e < e1; e += 16) {
                    const int2* pp = epack + e + 8 * g;
                    const i32x4 q0 = *(const i32x4*)pp;
                    const i32x4 q1 = *(const i32x4*)(pp + 2);
                    const i32x4 q2 = *(const i32x4*)(pp + 4);
                    const i32x4 q3 = *(const i32x4*)(pp + 6);
                    const u32x2 v0 = *(const u32x2*)(Z8in + q0[0] + colB);
                    const u32x2 v1 = *(const u32x2*)(Z8in + q0[2] + colB);
                    const u32x2 v2 = *(const u32x2*)(Z8in + q1[0] + colB);
                    const u32x2 v3 = *(const u32x2*)(Z8in + q1[2] + colB);
                    const u32x2 v4 = *(const u32x2*)(Z8in + q2[0] + colB);
                    const u32x2 v5 = *(const u32x2*)(Z8in + q2[2] + colB);
                    const u32x2 v6 = *(const u32x2*)(Z8in + q3[0] + colB);
                    const u32x2 v7 = *(const u32x2*)(Z8in + q3[2] + colB);
                    float c0 = __int_as_float(q0[1]), c1 = __int_as_float(q0[3]);
                    float c2 = __int_as_float(q1[1]), c3 = __int_as_float(q1[3]);
                    float c4 = __int_as_float(q2[1]), c5 = __int_as_float(q2[3]);
                    float c6 = __int_as_float(q3[1]), c7 = __int_as_float(q3[3]);
                    #pragma unroll
                    for (int h = 0; h < 8; ++h) {
                        u32x2 vv; float cc;
                        switch (h) {
                            case 0: vv = v0; cc = c0; break;
                            case 1: vv = v1; cc = c1; break;
                            case 2: vv = v2; cc = c2; break;
                            case 3: vv = v3; cc = c3; break;
                            case 4: vv = v4; cc = c4; break;
                            case 5: vv = v5; cc = c5; break;
                            case 6: vv = v6; cc = c6; break;
                            default: vv = v7; cc = c7; break;
                        }
                        f32x2 p0 = __builtin_amdgcn_cvt_pk_f32_fp8(vv[0], false);
                        f32x2 p1 = __builtin_amdgcn_cvt_pk_f32_fp8(vv[0], true);
                        f32x2 p2 = __builtin_amdgcn_cvt_pk_f32_fp8(vv[1], false);
                        f32x2 p3 = __builtin_amdgcn_cvt_pk_f32_fp8(vv[1], true);
                        a0 += cc * p0; a1 += cc * p1; a2 += cc * p2; a3 += cc * p3;
                    }
                }
            }
            float a[8] = {a0[0], a0[1], a1[0], a1[1], a2[0], a2[1], a3[0], a3[1]};
            #pragma unroll
            for (int j = 0; j < 8; ++j) a[j] += __shfl_xor(a[j], 32);
            if (g == 0) {
                u16x8 z;
                #pragma unroll
                for (int j = 0; j < 8; ++j) z[j] = f2b(a[j]);
                *(u16x8*)&abuf[buf][nl * ASTRIDE + colB] = z;
            }
        }
    };

    // ---------------- consumer: 16 nodes x 256 chans, fully wave-private --
    auto consume_tile = [&](int tile, int buf) {
        int c = wave - 4;                    // 0,1
        int mbase = tile * 32;
        int nodeRow = c * 16 + c16;          // node within tile for A/D column

        // A fragments from LDS (8 K-steps)
        bf16x8 nf[8];
        #pragma unroll
        for (int ks = 0; ks < 8; ++ks)
            nf[ks] = __builtin_bit_cast(bf16x8,
                *(const u16x8*)&abuf[buf][nodeRow * ASTRIDE + ks * 32 + q * 8]);

        f32x4 acc[16];
        #pragma unroll
        for (int ct = 0; ct < 16; ++ct) {
            acc[ct] = f32x4{0.f, 0.f, 0.f, 0.f};
            int woff = (ct * 16 + c16) * 32 + q * 8;
            #pragma unroll
            for (int ks = 0; ks < 8; ++ks) {
                bf16x8 wf = __builtin_bit_cast(bf16x8,
                    *(const u16x8*)(Bt + ks * 8192 + woff));
                acc[ct] = __builtin_amdgcn_mfma_f32_16x16x32_bf16(wf, nf[ks], acc[ct], 0, 0, 0);
            }
        }

        // stripe: row = node (c16), col = chan -- wave-private transpose
        #pragma unroll
        for (int ct = 0; ct < 16; ++ct) {
            u16x4 pk;
            pk[0] = f2b(acc[ct][0]);
            pk[1] = f2b(acc[ct][1]);
            pk[2] = f2b(acc[ct][2]);
            pk[3] = f2b(acc[ct][3]);
            *(u16x4*)&stripe[c][c16 * SSTRIDE + ct * 16 + q * 4] = pk;
        }
        // same-wave LDS RAW: compiler inserts lgkmcnt waits

        // drain: lane -> (node r = lane>>2, 64-chan chunk ck = lane&3)
        int r  = lane >> 2;
        int ck = lane & 3;
        int node = mbase + c * 16 + r;
        if (node >= N_NODES) return;
        int cb = ck * 64;
        float psum = 0.0f, psq = 0.0f;
        // pass 1: bias + GELU + residual; write Hbf; h (bf16) back into stripe
        #pragma unroll
        for (int i = 0; i < 8; ++i) {
            const u16x8 sv = *(const u16x8*)&stripe[c][r * SSTRIDE + cb + i * 8];
            const f32x4 b0 = *(const f32x4*)(bias + cb + i * 8);
            const f32x4 b1 = *(const f32x4*)(bias + cb + i * 8 + 4);
            const u16x8 hv = *(const u16x8*)(Hbf + (size_t)node * DIM + cb + i * 8);
            u16x8 hw;
            #pragma unroll
            for (int j = 0; j < 8; ++j) {
                float v = b2f(sv[j]) + (j < 4 ? b0[j] : b1[j - 4]);
                float hn = gelu_exact(v) + b2f(hv[j]);
                hw[j] = f2b(hn);
                psum += hn;
                psq += hn * hn;
            }
            *(u16x8*)(Hbf + (size_t)node * DIM + cb + i * 8) = hw;
            *(u16x8*)&stripe[c][r * SSTRIDE + cb + i * 8] = hw;
        }
        if (!doLN) return;
        // row stats across the 4 chunk-lanes of this node
        psum += __shfl_xor(psum, 1);
        psum += __shfl_xor(psum, 2);
        psq  += __shfl_xor(psq, 1);
        psq  += __shfl_xor(psq, 2);
        float mu = psum * (1.0f / DIM);
        float var = fmaxf(psq * (1.0f / DIM) - mu * mu, 0.0f);
        float rs = rsqrtf(var + EPS);
        // pass 2: LN -> fp8 Z8 (reads bf16 h from stripe)
        #pragma unroll
        for (int i2 = 0; i2 < 4; ++i2) {
            int c0 = cb + i2 * 16;
            const u16x8 h0 = *(const u16x8*)&stripe[c][r * SSTRIDE + c0];
            const u16x8 h1 = *(const u16x8*)&stripe[c][r * SSTRIDE + c0 + 8];
            unsigned int pk[4];
            #pragma unroll
            for (int k = 0; k < 4; ++k) {
                const f32x4 ww = *(const f32x4*)(lnw + c0 + k * 4);
                const f32x4 lb = *(const f32x4*)(lnb + c0 + k * 4);
                float y0, y1, y2, y3;
                if (k < 2) {
                    y0 = (b2f(h0[k * 4 + 0]) - mu) * rs * ww[0] + lb[0];
                    y1 = (b2f(h0[k * 4 + 1]) - mu) * rs * ww[1] + lb[1];
                    y2 = (b2f(h0[k * 4 + 2]) - mu) * rs * ww[2] + lb[2];
                    y3 = (b2f(h0[k * 4 + 3]) - mu) * rs * ww[3] + lb[3];
                } else {
                    y0 = (b2f(h1[(k - 2) * 4 + 0]) - mu) * rs * ww[0] + lb[0];
                    y1 = (b2f(h1[(k - 2) * 4 + 1]) - mu) * rs * ww[1] + lb[1];
                    y2 = (b2f(h1[(k - 2) * 4 + 2]) - mu) * rs * ww[2] + lb[2];
                    y3 = (b2f(h1[(k - 2) * 4 + 3]) - mu) * rs * ww[3] + lb[3];
                }
                pk[k] = pack_fp8x4(y0, y1, y2, y3);
            }
            uint4 st = make_uint4(pk[0], pk[1], pk[2], pk[3]);
            *(uint4*)(Z8out + (size_t)node * DIM + c0) = st;
        }
    };

    // ---------------- pipeline ----------------
    if (wave < 4) gather_tile(blockIdx.x, 0);
    __syncthreads();
    for (int it = 0; it < nt; ++it) {
        if (wave < 4) {
            if (it + 1 < nt) gather_tile(blockIdx.x + (it + 1) * GRIDB, (it + 1) & 1);
        } else {
            consume_tile(blockIdx.x + it * GRIDB, it & 1);
        }
        __syncthreads();
    }
}

// ---- final GEMM: out = Hbf @ post_w + post_b (fp32 out) -----------------
__global__ __launch_bounds__(256, 4) void gemm_out_kernel(const unsigned short* __restrict__ A,
                                                          const unsigned short* __restrict__ Bt,
                                                          float* __restrict__ C,
                                                          const float* __restrict__ bias) {
    int tid = threadIdx.x;
    int wave = tid >> 6;
    int lane = tid & 63;
    int q = lane >> 4;
    int c16 = lane & 15;
    int mbase = blockIdx.x * 32;
    int cbase = wave * 64;

    const unsigned short* aptr[2];
    #pragma unroll
    for (int nt = 0; nt < 2; ++nt) {
        int row = mbase + nt * 16 + c16;
        if (row >= N_NODES) row = N_NODES - 1;
        aptr[nt] = A + (size_t)row * DIM + q * 8;
    }
    int woff[4];
    #pragma unroll
    for (int ct = 0; ct < 4; ++ct)
        woff[ct] = (cbase + ct * 16 + c16) * 32 + q * 8;

    f32x4 acc[2][4] = {};
    #pragma unroll
    for (int ks = 0; ks < 8; ++ks) {
        bf16x8 nf[2], wf[4];
        #pragma unroll
        for (int nt = 0; nt < 2; ++nt)
            nf[nt] = __builtin_bit_cast(bf16x8, *(const u16x8*)(aptr[nt] + ks * 32));
        #pragma unroll
        for (int ct = 0; ct < 4; ++ct)
            wf[ct] = __builtin_bit_cast(bf16x8, *(const u16x8*)(Bt + ks * 8192 + woff[ct]));
        #pragma unroll
        for (int nt = 0; nt < 2; ++nt)
            #pragma unroll
            for (int ct = 0; ct < 4; ++ct)
                acc[nt][ct] = __builtin_amdgcn_mfma_f32_16x16x32_bf16(nf[nt], wf[ct], acc[nt][ct], 0, 0, 0);
    }

    float bb[4];
    #pragma unroll
    for (int ct = 0; ct < 4; ++ct)
        bb[ct] = bias[cbase + ct * 16 + c16];
    #pragma unroll
    for (int nt = 0; nt < 2; ++nt) {
        #pragma unroll
        for (int j = 0; j < 4; ++j) {
            int node = mbase + nt * 16 + q * 4 + j;
            if (node >= N_NODES) continue;
            #pragma unroll
            for (int ct = 0; ct < 4; ++ct) {
                int chan = cbase + ct * 16 + c16;
                C[(size_t)node * DIM + chan] = acc[nt][ct][j] + bb[ct];
            }
        }
    }
}

// ---- launch -------------------------------------------------------------
extern "C" void kernel_launch(void* const* d_in, const int* in_sizes, int n_in,
                              void* d_out, int out_size, void* d_ws, size_t ws_size,
                              hipStream_t stream) {
    const int*   ei     = (const int*)d_in[1];
    const int*   src    = ei;
    const int*   dst    = ei + N_EDGES;
    const float* ew     = (const float*)d_in[2];
    const float* emb    = (const float*)d_in[3];
    const float* ln_w   = (const float*)d_in[4];
    const float* ln_b   = (const float*)d_in[5];
    const float* conv_w = (const float*)d_in[6];
    const float* conv_b = (const float*)d_in[7];
    const float* post_w = (const float*)d_in[8];
    const float* post_b = (const float*)d_in[9];
    float* out = (float*)d_out;

    char* w = (char*)d_ws;
    size_t off = 0;
    auto alloc = [&](size_t bytes) -> char* {
        char* p = w + off;
        off += (bytes + 255) & ~(size_t)255;
        return p;
    };
    unsigned long long* cnt64 = (unsigned long long*)alloc((size_t)N_NODES * 8);
    float* dinv   = (float*)alloc((size_t)N_NODES * 4);
    int*   rank   = (int*)alloc((size_t)N_EDGES * 4);
    int*   rowptr = (int*)alloc((size_t)(N_NODES + 1) * 4);
    int*   bsum   = (int*)alloc(256 * 4);
    int*   boff   = (int*)alloc(256 * 4);
    int2*  epack  = (int2*)alloc((size_t)EPACK_CAP * 8);
    unsigned short* Wt  = (unsigned short*)alloc((size_t)5 * 65536 * 2);
    unsigned char*  Z8a = (unsigned char*)alloc((size_t)N_NODES * DIM);
    unsigned char*  Z8b = (unsigned char*)alloc((size_t)N_NODES * DIM);
    unsigned short* Hbf = (unsigned short*)alloc((size_t)N_NODES * DIM * 2);

    hipMemsetAsync(cnt64, 0, (size_t)N_NODES * 8, stream);
    hipMemsetAsync(epack, 0, (size_t)EPACK_CAP * 8, stream);
    hist_kernel<<<N_EDGES / 256, 256, 0, stream>>>(dst, ew, cnt64, rank);
    scan_a_kernel<<<SCAN_B, 256, 0, stream>>>(cnt64, dinv, bsum);
    scan_b_kernel<<<1, 256, 0, stream>>>(bsum, boff, rowptr);
    scan_c_kernel<<<SCAN_B, 256, 0, stream>>>(cnt64, boff, rowptr);
    fill_kernel<<<N_EDGES / 256, 256, 0, stream>>>(src, dst, ew, dinv, rowptr, rank, epack);
    convw_kernel<<<(5 * 65536) / 256, 256, 0, stream>>>(conv_w, post_w, Wt);

    ln_cast_kernel<<<N_NODES / 4, 256, 0, stream>>>(emb, ln_w, ln_b, Z8a, Hbf);
    for (int l = 0; l < NLAYERS; ++l) {
        const unsigned char* zin  = (l & 1) ? Z8b : Z8a;
        unsigned char*       zout = (l & 1) ? Z8a : Z8b;
        int doLN = (l < NLAYERS - 1) ? 1 : 0;
        const float* nlw = doLN ? (ln_w + (l + 1) * DIM) : ln_w;
        const float* nlb = doLN ? (ln_b + (l + 1) * DIM) : ln_b;
        layer_kernel<<<GRIDB, 384, 0, stream>>>(zin, rowptr, epack, dinv,
                                                Wt + (size_t)l * 65536,
                                                conv_b + (size_t)l * DIM, Hbf,
                                                nlw, nlb, zout, doLN);
    }
    gemm_out_kernel<<<(N_NODES + 31) / 32, 256, 0, stream>>>(Hbf, Wt + (size_t)4 * 65536, out, post_b);
}